// Round 1
// baseline (463.326 us; speedup 1.0000x reference)
//
#include <hip/hip_runtime.h>

// Output = jacobi(X, Mask1, 100) on 1024x1024 fp32 grid:
//   x_next[i][j] = 0.25*(x[i-1][j]+x[i+1][j]+x[i][j-1]+x[i][j+1])*m[i][j]
//                + x[i][j]*(1-m[i][j]),   zero padding (SAME conv).
// All multigrid restriction/prolongation in the reference is dead code for
// the returned value (grids[0] is never mutated).

#define H 1024
#define W 1024
#define NT 100

__global__ __launch_bounds__(256) void jacobi_step(
    const float* __restrict__ x, const float* __restrict__ m,
    float* __restrict__ out) {
    int j = blockIdx.x * 64 + threadIdx.x;   // col (coalesced along wave)
    int i = blockIdx.y * 4 + threadIdx.y;    // row
    int idx = i * W + j;
    float c  = x[idx];
    float up = (i > 0)     ? x[idx - W] : 0.f;
    float dn = (i < H - 1) ? x[idx + W] : 0.f;
    float lf = (j > 0)     ? x[idx - 1] : 0.f;
    float rt = (j < W - 1) ? x[idx + 1] : 0.f;
    float mm = m[idx];
    out[idx] = 0.25f * (up + dn + lf + rt) * mm + c * (1.f - mm);
}

extern "C" void kernel_launch(void* const* d_in, const int* in_sizes, int n_in,
                              void* d_out, int out_size, void* d_ws, size_t ws_size,
                              hipStream_t stream) {
    const float* X = (const float*)d_in[0];   // (1,1,1024,1024)
    const float* M = (const float*)d_in[1];   // Mask1 (1,1,1024,1024)
    float* out = (float*)d_out;
    float* ws  = (float*)d_ws;                // 4 MB ping buffer

    dim3 block(64, 4);
    dim3 grid(W / 64, H / 4);

    // Ping-pong: odd steps write ws, even steps write out.
    // Step 1 reads X (d_in) directly -> ws fully initialized before any read.
    // Step 100 (even) writes d_out. Deterministic, no state carried across calls.
    const float* src = X;
    for (int t = 1; t <= NT; ++t) {
        float* dst = (t & 1) ? ws : out;
        jacobi_step<<<grid, block, 0, stream>>>(src, M, dst);
        src = dst;
    }
}

// Round 2
// 215.970 us; speedup vs baseline: 2.1453x; 2.1453x over previous
//
#include <hip/hip_runtime.h>

// Output = jacobi(X, Mask1, 100) — the multigrid sweeps in the reference are
// dead code for the returned value (grids[0] is never mutated).
// Trapezoidal temporal blocking: 10 launches x 10 fused iterations in LDS.

#define W 1024
#define H 1024
#define TILE 64
#define TI 10                    // fused iterations per launch
#define OS (TILE - 2 * TI)       // 44 valid output per tile
#define LS 68                    // padded LDS row stride (floats), 272B = 16B-aligned
#define NB ((W + OS - 1) / OS)   // 24
#define NLAUNCH 10               // NLAUNCH * TI = 100

__device__ __forceinline__ void jstep(
    const float (*__restrict__ src)[LS], float (*__restrict__ dst)[LS],
    const float (&m)[4][4], int R0, int C0, int pc)
{
    // rolling row vectors: rows R0-1 .. R0+4, cols C0..C0+3
    float4 rv[6];
    #pragma unroll
    for (int k = 0; k < 6; ++k) {
        int r = R0 - 1 + k;
        if (r >= 0 && r < TILE)
            rv[k] = *(const float4*)&src[r][C0];
        else
            rv[k] = make_float4(0.f, 0.f, 0.f, 0.f);
    }
    #pragma unroll
    for (int i = 0; i < 4; ++i) {
        int r = R0 + i;
        if (r < 1 || r > TILE - 2) continue;       // tile-edge rows frozen
        float4 up = rv[i], ce = rv[i + 1], dn = rv[i + 2];
        float lsc = (C0 >= 1) ? src[r][C0 - 1] : 0.f;
        float rsc = (C0 + 4 <= TILE - 1) ? src[r][C0 + 4] : 0.f;
        float4 nv; float s;
        s = up.x + dn.x + lsc  + ce.y;  nv.x = ce.x + m[i][0] * (0.25f * s - ce.x);
        s = up.y + dn.y + ce.x + ce.z;  nv.y = ce.y + m[i][1] * (0.25f * s - ce.y);
        s = up.z + dn.z + ce.y + ce.w;  nv.z = ce.z + m[i][2] * (0.25f * s - ce.z);
        s = up.w + dn.w + ce.z + rsc;   nv.w = ce.w + m[i][3] * (0.25f * s - ce.w);
        if (pc == 0)  nv.x = ce.x;                 // tile-edge cols frozen
        if (pc == 15) nv.w = ce.w;
        *(float4*)&dst[r][C0] = nv;
    }
}

__global__ __launch_bounds__(256, 4) void jacobi_trap(
    const float* __restrict__ xin, const float* __restrict__ mask,
    float* __restrict__ xout)
{
    __shared__ float A[TILE][LS];
    __shared__ float B[TILE][LS];

    const int tid = threadIdx.x;
    const int gx0 = (int)blockIdx.x * OS - TI;
    const int gy0 = (int)blockIdx.y * OS - TI;

    // load 64x64 x tile (zeros outside domain), coalesced rows
    #pragma unroll
    for (int k = 0; k < 16; ++k) {
        int idx = tid + k * 256;
        int r = idx >> 6, c = idx & 63;
        int gr = gy0 + r, gc = gx0 + c;
        float v = 0.f;
        if ((unsigned)gr < (unsigned)H && (unsigned)gc < (unsigned)W)
            v = xin[gr * W + gc];
        A[r][c] = v;
    }
    // B's frozen edge ring: init to 0 so halo cells never read garbage/NaN.
    if (tid < TILE) {
        B[0][tid] = 0.f;  B[TILE - 1][tid] = 0.f;
        B[tid][0] = 0.f;  B[tid][TILE - 1] = 0.f;
    }

    // mask for my 4x4 patch -> registers (reused across all TI iterations)
    const int pr = tid >> 4, pc = tid & 15;
    const int R0 = pr * 4, C0 = pc * 4;
    float m[4][4];
    #pragma unroll
    for (int i = 0; i < 4; ++i) {
        #pragma unroll
        for (int j = 0; j < 4; ++j) {
            int gr = gy0 + R0 + i, gc = gx0 + C0 + j;
            m[i][j] = ((unsigned)gr < (unsigned)H && (unsigned)gc < (unsigned)W)
                        ? mask[gr * W + gc] : 0.f;
        }
    }

    __syncthreads();

    #pragma unroll 1
    for (int it = 0; it < TI / 2; ++it) {
        jstep(A, B, m, R0, C0, pc);
        __syncthreads();
        jstep(B, A, m, R0, C0, pc);
        __syncthreads();
    }

    // TI even -> result in A; write central OS x OS window
    #pragma unroll
    for (int i = 0; i < 4; ++i) {
        int r = R0 + i;
        if (r < TI || r >= TILE - TI) continue;
        int gr = gy0 + r;
        if (gr >= H) continue;                     // gr >= 0 guaranteed (r >= TI)
        #pragma unroll
        for (int j = 0; j < 4; ++j) {
            int c = C0 + j;
            if (c < TI || c >= TILE - TI) continue;
            int gc = gx0 + c;
            if (gc >= W) continue;
            xout[gr * W + gc] = A[r][c];
        }
    }
}

extern "C" void kernel_launch(void* const* d_in, const int* in_sizes, int n_in,
                              void* d_out, int out_size, void* d_ws, size_t ws_size,
                              hipStream_t stream) {
    const float* X = (const float*)d_in[0];   // (1,1,1024,1024)
    const float* M = (const float*)d_in[1];   // Mask1
    float* out = (float*)d_out;
    float* ws  = (float*)d_ws;                // 4 MB ping buffer

    dim3 grid(NB, NB), block(256);
    // l=0: X->ws; alternate; l=9 (odd) -> out. Every buffer written before read.
    const float* src = X;
    for (int l = 0; l < NLAUNCH; ++l) {
        float* dst = (l & 1) ? out : ws;
        jacobi_trap<<<grid, block, 0, stream>>>(src, M, dst);
        src = dst;
    }
}